// Round 1
// baseline (22582.660 us; speedup 1.0000x reference)
//
#include <hip/hip_runtime.h>
#include <hip/hip_bf16.h>

#define TT 2048
#define DD 768
#define HH 6
#define HDIM 128
#define NL 12
#define NBL 16
#define BLKSZ 128
#define DFF 3072
#define VP 50304
#define NV 50257
#define EPSF 1.1920929e-07f

// ---------- reduction helpers ----------
__device__ __forceinline__ float wave_sum(float v){
#pragma unroll
  for (int o = 32; o > 0; o >>= 1) v += __shfl_xor(v, o);
  return v;
}
__device__ __forceinline__ float wave_max(float v){
#pragma unroll
  for (int o = 32; o > 0; o >>= 1) v = fmaxf(v, __shfl_xor(v, o));
  return v;
}
__device__ __forceinline__ float block_sum(float v){
  __shared__ float sh[9];
  int lane = threadIdx.x & 63, w = threadIdx.x >> 6;
  v = wave_sum(v);
  if (lane == 0) sh[w] = v;
  __syncthreads();
  if (threadIdx.x == 0){
    float tot = 0.f;
    int nw = (blockDim.x + 63) >> 6;
    for (int i = 0; i < nw; i++) tot += sh[i];
    sh[8] = tot;
  }
  __syncthreads();
  return sh[8];
}

// ---------- docs + block masks ----------
__global__ void k_docs_masks(const int* __restrict__ seq, const int* __restrict__ swnb,
                             int* __restrict__ docs, int* __restrict__ bmask){
  if (threadIdx.x != 0) return;
  int c = 0;
  for (int t = 0; t < TT; t++){ c += (seq[t] == 50256); docs[t] = c; }
  int dlo[NBL], dhi[NBL];
  for (int b = 0; b < NBL; b++){ dlo[b] = docs[b*BLKSZ]; dhi[b] = docs[b*BLKSZ + BLKSZ-1]; }
  int allb[NBL][NBL], partb[NBL][NBL];
  for (int i = 0; i < NBL; i++)
    for (int j = 0; j < NBL; j++){
      int a = (i >= j) && (dlo[i] <= dhi[j]) && (dhi[i] >= dlo[j]);
      int f = (i >  j) && (dlo[i] == dhi[j]) && (dhi[i] == dlo[j]);
      allb[i][j] = f; partb[i][j] = a && !f;
    }
  int sws[2]; sws[0] = swnb[0]; sws[1] = swnb[0] / 2;
  for (int m = 0; m < 2; m++){
    int sw = sws[m];
    for (int i = 0; i < NBL; i++){
      int fullcnt = 0;
      for (int j = 0; j < NBL; j++) fullcnt += allb[i][j];
      int pth = sw - fullcnt; if (pth < 1) pth = 1;
      int pr = 0, fr = 0;
      for (int j = NBL-1; j >= 0; j--){
        int kp = partb[i][j] && (pr < pth);
        int kf = allb[i][j]  && (fr < sw - 1);
        bmask[(m*2+0)*NBL*NBL + i*NBL + j] = kf;
        bmask[(m*2+1)*NBL*NBL + i*NBL + j] = kp;
        pr += partb[i][j]; fr += allb[i][j];
      }
    }
  }
}

// ---------- rotary tables ----------
__global__ void k_rotary(float* __restrict__ cosb, float* __restrict__ sinb){
  int t = blockIdx.x, j = threadIdx.x;  // 64 threads
  float c = 1.f, s = 0.f;
  if (j < 32){
    float af = powf(1.0f/1024.0f, (float)j / 31.0f);
    float th = (float)t * af;
    c = cosf(th); s = sinf(th);
  }
  cosb[t*64 + j] = c; sinb[t*64 + j] = s;
}

// ---------- embedding gather + rmsnorm, ve gathers ----------
__global__ void k_embed(const int* __restrict__ seq, const float* __restrict__ embw,
                        const float* __restrict__ vew, float* __restrict__ x,
                        float* __restrict__ x0, float* __restrict__ veg){
  int t = blockIdx.x;
  int tok = seq[t];
  const float* row = embw + (size_t)tok * DD;
  float ss = 0.f;
  for (int d = threadIdx.x; d < DD; d += blockDim.x){ float v = row[d]; ss += v*v; }
  float tot = block_sum(ss);
  float rn = rsqrtf(tot / DD + EPSF);
  for (int d = threadIdx.x; d < DD; d += blockDim.x){
    float v = row[d] * rn;
    x[(size_t)t*DD + d] = v; x0[(size_t)t*DD + d] = v;
  }
  for (int j = 0; j < 3; j++){
    const float* vr = vew + ((size_t)j*NV + tok) * DD;
    float* dst = veg + ((size_t)j*TT + t) * DD;
    for (int d = threadIdx.x; d < DD; d += blockDim.x) dst[d] = vr[d];
  }
}

// ---------- row rmsnorm ----------
__global__ void k_rmsnorm(const float* __restrict__ in, float* __restrict__ out){
  int t = blockIdx.x;
  const float* r = in + (size_t)t * DD;
  float ss = 0.f;
  for (int d = threadIdx.x; d < DD; d += blockDim.x){ float v = r[d]; ss += v*v; }
  float tot = block_sum(ss);
  float rn = rsqrtf(tot / DD + EPSF);
  float* o = out + (size_t)t * DD;
  for (int d = threadIdx.x; d < DD; d += blockDim.x) o[d] = r[d] * rn;
}

// ---------- tiled fp32 GEMM: C[M,N] (+)= A[M,K] * B[N,K]^T ----------
template<int BETA>
__global__ __launch_bounds__(256) void k_gemm(const float* __restrict__ A, const float* __restrict__ B,
                                              float* __restrict__ C, int M, int N, int K){
  __shared__ float As[16][65];
  __shared__ float Bs[16][65];
  int bm = blockIdx.y * 64, bn = blockIdx.x * 64;
  int tid = threadIdx.x;
  int tx = tid & 15, ty = tid >> 4;
  int lm = tid >> 2, lk = (tid & 3) << 2;
  float acc[4][4] = {};
  for (int k0 = 0; k0 < K; k0 += 16){
    float4 av = *(const float4*)(A + (size_t)(bm + lm) * K + k0 + lk);
    float4 bv = *(const float4*)(B + (size_t)(bn + lm) * K + k0 + lk);
    As[lk+0][lm] = av.x; As[lk+1][lm] = av.y; As[lk+2][lm] = av.z; As[lk+3][lm] = av.w;
    Bs[lk+0][lm] = bv.x; Bs[lk+1][lm] = bv.y; Bs[lk+2][lm] = bv.z; Bs[lk+3][lm] = bv.w;
    __syncthreads();
#pragma unroll
    for (int kk = 0; kk < 16; kk++){
      float a[4], b[4];
#pragma unroll
      for (int i = 0; i < 4; i++){ a[i] = As[kk][ty*4 + i]; b[i] = Bs[kk][tx*4 + i]; }
#pragma unroll
      for (int i = 0; i < 4; i++)
#pragma unroll
        for (int j = 0; j < 4; j++) acc[i][j] += a[i] * b[j];
    }
    __syncthreads();
  }
#pragma unroll
  for (int i = 0; i < 4; i++){
    float* cp = C + (size_t)(bm + ty*4 + i) * N + bn + tx*4;
    if (BETA){
#pragma unroll
      for (int j = 0; j < 4; j++) cp[j] += acc[i][j];
    } else {
#pragma unroll
      for (int j = 0; j < 4; j++) cp[j] = acc[i][j];
    }
  }
}

// ---------- per-head q/k rmsnorm + rotary (one wave per (t,h)) ----------
__global__ void k_qknorm_rope(float* __restrict__ qkv, const float* __restrict__ cosb,
                              const float* __restrict__ sinb){
  int wv = threadIdx.x >> 6, lane = threadIdx.x & 63;
  int idx = blockIdx.x * 4 + wv;
  int t = idx / HH, h = idx - t * HH;
  float c = cosb[t*64 + lane], s = sinb[t*64 + lane];
#pragma unroll
  for (int w = 0; w < 2; w++){
    float* p = qkv + (size_t)t*2304 + w*768 + h*HDIM;
    float v1 = p[lane], v2 = p[lane + 64];
    float ss = wave_sum(v1*v1 + v2*v2);
    float rn = rsqrtf(ss / 128.f + EPSF);
    v1 *= rn; v2 *= rn;
    p[lane]      = v1 * c + v2 * s;
    p[lane + 64] = -v1 * s + v2 * c;
  }
}

// ---------- v = lam0*v + lam1*ve ----------
__global__ void k_vmix(float* __restrict__ qkv, const float* __restrict__ ve,
                       const float* __restrict__ lam, int layer){
  int i = blockIdx.x * 256 + threadIdx.x;
  float l0 = lam[layer*2], l1 = lam[layer*2 + 1];
  int t = i / DD, d = i - t * DD;
  float* vp = qkv + (size_t)t*2304 + 1536 + d;
  float v = *vp * l0;
  if (ve) v += l1 * ve[i];
  *vp = v;
}

// ---------- fused attention: one (head, 8-query-row) block ----------
#define QR 8
__global__ __launch_bounds__(256) void k_attn(const float* __restrict__ qkv, float* __restrict__ y,
                                              const int* __restrict__ docs,
                                              const int* __restrict__ kfm, const int* __restrict__ kpm){
  __shared__ float sc[QR][TT];     // 64 KB
  __shared__ float qs[QR][HDIM];   // 4 KB
  __shared__ float rinv[QR];
  int h = blockIdx.x;
  int r0 = blockIdx.y * QR;
  int tid = threadIdx.x;
  for (int i = tid; i < QR*HDIM; i += 256){
    int r = i >> 7, d = i & 127;
    qs[r][d] = qkv[(size_t)(r0 + r)*2304 + h*HDIM + d];
  }
  __syncthreads();
  int bt = r0 >> 7;
  int dq[QR];
#pragma unroll
  for (int r = 0; r < QR; r++) dq[r] = docs[r0 + r];
  for (int s = tid; s < TT; s += 256){
    const float* kr = qkv + (size_t)s*2304 + 768 + h*HDIM;
    float acc[QR] = {};
#pragma unroll 8
    for (int d = 0; d < HDIM; d += 4){
      float4 kv = *(const float4*)(kr + d);
#pragma unroll
      for (int r = 0; r < QR; r++)
        acc[r] += kv.x*qs[r][d] + kv.y*qs[r][d+1] + kv.z*qs[r][d+2] + kv.w*qs[r][d+3];
    }
    int bs = s >> 7;
    int kf = kfm[bt*NBL + bs], kp = kpm[bt*NBL + bs];
    int ds = docs[s];
#pragma unroll
    for (int r = 0; r < QR; r++){
      int t = r0 + r;
      bool m = kf || (kp && (s <= t) && (ds == dq[r]));
      sc[r][s] = m ? acc[r] * 0.12f : -1e30f;
    }
  }
  __syncthreads();
  int wv = tid >> 6, lane = tid & 63;
  for (int r = wv; r < QR; r += 4){
    float mx = -1e30f;
    for (int s = lane; s < TT; s += 64) mx = fmaxf(mx, sc[r][s]);
    mx = wave_max(mx);
    float sum = 0.f;
    for (int s = lane; s < TT; s += 64){ float e = __expf(sc[r][s] - mx); sc[r][s] = e; sum += e; }
    sum = wave_sum(sum);
    if (lane == 0) rinv[r] = 1.f / sum;
  }
  __syncthreads();
  int r = tid >> 5, c4 = tid & 31;
  const float* vb = qkv + 1536 + h*HDIM + c4*4;
  float ax = 0, ay = 0, az = 0, aw = 0;
  for (int s = 0; s < TT; s++){
    float p = sc[r][s];
    float4 vv = *(const float4*)(vb + (size_t)s*2304);
    ax += p*vv.x; ay += p*vv.y; az += p*vv.z; aw += p*vv.w;
  }
  float inv = rinv[r];
  float4* yo = (float4*)(y + (size_t)(r0 + r)*DD + h*HDIM + c4*4);
  *yo = make_float4(ax*inv, ay*inv, az*inv, aw*inv);
}

// ---------- elementwise ----------
__global__ void k_relusq(float* __restrict__ h){
  int i = blockIdx.x * 256 + threadIdx.x;
  float v = h[i]; v = fmaxf(v, 0.f); h[i] = v * v;
}
__global__ void k_blockmix(float* __restrict__ x, const float* __restrict__ x0,
                           const float* __restrict__ bl, int layer){
  int i = blockIdx.x * 256 + threadIdx.x;
  x[i] = bl[layer*2] * x[i] + bl[layer*2 + 1] * x0[i];
}
__global__ void k_skipadd(float* __restrict__ x, const float* __restrict__ sk,
                          const float* __restrict__ sw, int j){
  int i = blockIdx.x * 256 + threadIdx.x;
  x[i] += sw[j] * sk[i];
}

// ---------- lm_head GEMM fused with logit transform + expsum ----------
__global__ __launch_bounds__(256) void k_loss_gemm(const float* __restrict__ A, const float* __restrict__ B,
                                                   const int* __restrict__ tgt, float* __restrict__ rowsum,
                                                   float* __restrict__ tl){
  __shared__ float As[16][65];
  __shared__ float Bs[16][65];
  __shared__ float red[64][17];
  int bm = blockIdx.y * 64, bn = blockIdx.x * 64;
  int tid = threadIdx.x, tx = tid & 15, ty = tid >> 4;
  int lm = tid >> 2, lk = (tid & 3) << 2;
  float acc[4][4] = {};
  for (int k0 = 0; k0 < DD; k0 += 16){
    float4 av = *(const float4*)(A + (size_t)(bm + lm) * DD + k0 + lk);
    float4 bv = *(const float4*)(B + (size_t)(bn + lm) * DD + k0 + lk);
    As[lk+0][lm] = av.x; As[lk+1][lm] = av.y; As[lk+2][lm] = av.z; As[lk+3][lm] = av.w;
    Bs[lk+0][lm] = bv.x; Bs[lk+1][lm] = bv.y; Bs[lk+2][lm] = bv.z; Bs[lk+3][lm] = bv.w;
    __syncthreads();
#pragma unroll
    for (int kk = 0; kk < 16; kk++){
      float a[4], b[4];
#pragma unroll
      for (int i = 0; i < 4; i++){ a[i] = As[kk][ty*4 + i]; b[i] = Bs[kk][tx*4 + i]; }
#pragma unroll
      for (int i = 0; i < 4; i++)
#pragma unroll
        for (int j = 0; j < 4; j++) acc[i][j] += a[i] * b[j];
    }
    __syncthreads();
  }
  const float INVS = 0.0048112522432469f; // 1/(7.5*sqrt(768))
#pragma unroll
  for (int i = 0; i < 4; i++){
    int row = bm + ty*4 + i;
    int tg = tgt[row];
    float rs = 0.f;
#pragma unroll
    for (int j = 0; j < 4; j++){
      int col = bn + tx*4 + j;
      float lg = 30.f / (1.f + expf(-acc[i][j] * INVS));
      rs += expf(lg);
      if (col == tg) tl[row] = lg;
    }
    red[ty*4 + i][tx] = rs;
  }
  __syncthreads();
  if (tid < 64){
    float s = 0.f;
#pragma unroll
    for (int k = 0; k < 16; k++) s += red[tid][k];
    atomicAdd(&rowsum[bm + tid], s);
  }
}

__global__ void k_loss_final(const float* __restrict__ rowsum, const float* __restrict__ tl,
                             float* __restrict__ out){
  float a = 0.f;
  for (int t = threadIdx.x; t < TT; t += 256) a += logf(rowsum[t]) - tl[t];
  a = block_sum(a);
  if (threadIdx.x == 0) out[0] = a / TT;
}

extern "C" void kernel_launch(void* const* d_in, const int* in_sizes, int n_in,
                              void* d_out, int out_size, void* d_ws, size_t ws_size,
                              hipStream_t stream){
  const int*   seq   = (const int*)d_in[0];
  const int*   tgt   = (const int*)d_in[1];
  const int*   swnb  = (const int*)d_in[2];
  const float* embw  = (const float*)d_in[3];
  const float* vew   = (const float*)d_in[4];
  const float* qkvw  = (const float*)d_in[5];
  const float* alam  = (const float*)d_in[6];
  const float* aproj = (const float*)d_in[7];
  const float* fcw   = (const float*)d_in[8];
  const float* mproj = (const float*)d_in[9];
  const float* blam  = (const float*)d_in[10];
  const float* skw   = (const float*)d_in[11];
  const float* lmw   = (const float*)d_in[12];

  float* base = (float*)d_ws;
  size_t off = 0;
  auto alloc = [&](size_t n){ float* p = base + off; off += n; return p; };
  float* x    = alloc((size_t)TT*DD);
  float* x0   = alloc((size_t)TT*DD);
  float* xn   = alloc((size_t)TT*DD);
  float* y    = alloc((size_t)TT*DD);
  float* qkv  = alloc((size_t)TT*2304);
  float* hbuf = alloc((size_t)TT*DFF);
  float* veg  = alloc((size_t)3*TT*DD);
  float* skips= alloc((size_t)6*TT*DD);
  float* cosb = alloc((size_t)TT*64);
  float* sinb = alloc((size_t)TT*64);
  float* rowsum = alloc(TT);
  float* tl     = alloc(TT);
  int* docs  = (int*)alloc(TT);
  int* bmask = (int*)alloc(4*NBL*NBL);

  k_docs_masks<<<1, 64, 0, stream>>>(seq, swnb, docs, bmask);
  k_rotary<<<TT, 64, 0, stream>>>(cosb, sinb);
  k_embed<<<TT, 256, 0, stream>>>(seq, embw, vew, x, x0, veg);

  static const int msel[12] = {0,1,1,1,0,1, 1,0,1,1,1,0};
  const int NE = TT*DD/256;   // elementwise grid
  for (int i = 0; i < NL; i++){
    if (i >= 6){
      int j = i - 6;
      k_skipadd<<<NE, 256, 0, stream>>>(x, skips + (size_t)(5 - j)*TT*DD, skw, j);
    }
    k_blockmix<<<NE, 256, 0, stream>>>(x, x0, blam, i);
    if (i != 7){
      k_rmsnorm<<<TT, 256, 0, stream>>>(x, xn);
      dim3 g1(2304/64, TT/64);
      k_gemm<0><<<g1, 256, 0, stream>>>(xn, qkvw + (size_t)i*3*DD*DD, qkv, TT, 3*DD, DD);
      k_qknorm_rope<<<TT*HH/4, 256, 0, stream>>>(qkv, cosb, sinb);
      const float* vp = nullptr;
      if (i < 3) vp = veg + (size_t)i*TT*DD;
      else if (i >= 9) vp = veg + (size_t)(i - 9)*TT*DD;
      k_vmix<<<NE, 256, 0, stream>>>(qkv, vp, alam, i);
      const int* kfm = bmask + (msel[i]*2 + 0)*NBL*NBL;
      const int* kpm = bmask + (msel[i]*2 + 1)*NBL*NBL;
      dim3 ga(HH, TT/QR);
      k_attn<<<ga, 256, 0, stream>>>(qkv, y, docs, kfm, kpm);
      dim3 g2(DD/64, TT/64);
      k_gemm<1><<<g2, 256, 0, stream>>>(y, aproj + (size_t)i*DD*DD, x, TT, DD, DD);
    }
    k_rmsnorm<<<TT, 256, 0, stream>>>(x, xn);
    dim3 g3(DFF/64, TT/64);
    k_gemm<0><<<g3, 256, 0, stream>>>(xn, fcw + (size_t)i*DFF*DD, hbuf, TT, DFF, DD);
    k_relusq<<<TT*DFF/256, 256, 0, stream>>>(hbuf);
    dim3 g4(DD/64, TT/64);
    k_gemm<1><<<g4, 256, 0, stream>>>(hbuf, mproj + (size_t)i*DD*DFF, x, TT, DD, DFF);
    if (i < 6){
      hipMemcpyAsync(skips + (size_t)i*TT*DD, x, (size_t)TT*DD*sizeof(float),
                     hipMemcpyDeviceToDevice, stream);
    }
  }
  k_rmsnorm<<<TT, 256, 0, stream>>>(x, xn);
  hipMemsetAsync(rowsum, 0, TT*sizeof(float), stream);
  dim3 g5(VP/64, TT/64);
  k_loss_gemm<<<g5, 256, 0, stream>>>(xn, lmw, tgt, rowsum, tl);
  k_loss_final<<<1, 256, 0, stream>>>(rowsum, tl, (float*)d_out);
}

// Round 2
// 5409.739 us; speedup vs baseline: 4.1744x; 4.1744x over previous
//
#include <hip/hip_runtime.h>
#include <hip/hip_bf16.h>

#define TT 2048
#define DD 768
#define HH 6
#define HDIM 128
#define NL 12
#define NBL 16
#define BLKSZ 128
#define DFF 3072
#define VP 50304
#define NV 50257
#define EPSF 1.1920929e-07f

typedef unsigned short u16;
typedef __attribute__((ext_vector_type(8))) short short8v;
typedef __attribute__((ext_vector_type(4))) float f32x4;
typedef __attribute__((address_space(3))) void lds_void;
typedef __attribute__((address_space(1))) void gbl_void;

__device__ __forceinline__ u16 f2bf(float f){
  unsigned u = __float_as_uint(f);
  return (u16)((u + 0x7fffu + ((u >> 16) & 1u)) >> 16);
}
__device__ __forceinline__ void async16(const void* g, void* l){
  __builtin_amdgcn_global_load_lds((const gbl_void*)g, (lds_void*)l, 16, 0, 0);
}

// ---------- reduction helpers ----------
__device__ __forceinline__ float wave_sum(float v){
#pragma unroll
  for (int o = 32; o > 0; o >>= 1) v += __shfl_xor(v, o);
  return v;
}
__device__ __forceinline__ float wave_max(float v){
#pragma unroll
  for (int o = 32; o > 0; o >>= 1) v = fmaxf(v, __shfl_xor(v, o));
  return v;
}
__device__ __forceinline__ float block_sum(float v){
  __shared__ float sh[9];
  int lane = threadIdx.x & 63, w = threadIdx.x >> 6;
  v = wave_sum(v);
  if (lane == 0) sh[w] = v;
  __syncthreads();
  if (threadIdx.x == 0){
    float tot = 0.f;
    int nw = (blockDim.x + 63) >> 6;
    for (int i = 0; i < nw; i++) tot += sh[i];
    sh[8] = tot;
  }
  __syncthreads();
  return sh[8];
}

// ---------- fp32 -> bf16 bulk convert ----------
__global__ void k_f2bf(const float* __restrict__ in, u16* __restrict__ out, long ngrp){
  long stride = (long)gridDim.x * blockDim.x;
  for (long g = (long)blockIdx.x * blockDim.x + threadIdx.x; g < ngrp; g += stride){
    const float4* p = (const float4*)(in + g * 8);
    float4 a = p[0], b = p[1];
    u16 o[8] = { f2bf(a.x), f2bf(a.y), f2bf(a.z), f2bf(a.w),
                 f2bf(b.x), f2bf(b.y), f2bf(b.z), f2bf(b.w) };
    *(ulonglong2*)(out + g * 8) = *(const ulonglong2*)o;
  }
}

// ---------- docs + block masks ----------
__global__ void k_docs_masks(const int* __restrict__ seq, const int* __restrict__ swnb,
                             int* __restrict__ docs, int* __restrict__ bmask){
  if (threadIdx.x != 0) return;
  int c = 0;
  for (int t = 0; t < TT; t++){ c += (seq[t] == 50256); docs[t] = c; }
  int dlo[NBL], dhi[NBL];
  for (int b = 0; b < NBL; b++){ dlo[b] = docs[b*BLKSZ]; dhi[b] = docs[b*BLKSZ + BLKSZ-1]; }
  int allb[NBL][NBL], partb[NBL][NBL];
  for (int i = 0; i < NBL; i++)
    for (int j = 0; j < NBL; j++){
      int a = (i >= j) && (dlo[i] <= dhi[j]) && (dhi[i] >= dlo[j]);
      int f = (i >  j) && (dlo[i] == dhi[j]) && (dhi[i] == dlo[j]);
      allb[i][j] = f; partb[i][j] = a && !f;
    }
  int sws[2]; sws[0] = swnb[0]; sws[1] = swnb[0] / 2;
  for (int m = 0; m < 2; m++){
    int sw = sws[m];
    for (int i = 0; i < NBL; i++){
      int fullcnt = 0;
      for (int j = 0; j < NBL; j++) fullcnt += allb[i][j];
      int pth = sw - fullcnt; if (pth < 1) pth = 1;
      int pr = 0, fr = 0;
      for (int j = NBL-1; j >= 0; j--){
        int kp = partb[i][j] && (pr < pth);
        int kf = allb[i][j]  && (fr < sw - 1);
        bmask[(m*2+0)*NBL*NBL + i*NBL + j] = kf;
        bmask[(m*2+1)*NBL*NBL + i*NBL + j] = kp;
        pr += partb[i][j]; fr += allb[i][j];
      }
    }
  }
}

// ---------- rotary tables ----------
__global__ void k_rotary(float* __restrict__ cosb, float* __restrict__ sinb){
  int t = blockIdx.x, j = threadIdx.x;  // 64 threads
  float c = 1.f, s = 0.f;
  if (j < 32){
    float af = powf(1.0f/1024.0f, (float)j / 31.0f);
    float th = (float)t * af;
    c = cosf(th); s = sinf(th);
  }
  cosb[t*64 + j] = c; sinb[t*64 + j] = s;
}

// ---------- embedding gather + rmsnorm, ve gathers ----------
__global__ void k_embed(const int* __restrict__ seq, const float* __restrict__ embw,
                        const float* __restrict__ vew, float* __restrict__ x,
                        float* __restrict__ x0, float* __restrict__ veg){
  int t = blockIdx.x;
  int tok = seq[t];
  const float* row = embw + (size_t)tok * DD;
  float ss = 0.f;
  for (int d = threadIdx.x; d < DD; d += blockDim.x){ float v = row[d]; ss += v*v; }
  float tot = block_sum(ss);
  float rn = rsqrtf(tot / DD + EPSF);
  for (int d = threadIdx.x; d < DD; d += blockDim.x){
    float v = row[d] * rn;
    x[(size_t)t*DD + d] = v; x0[(size_t)t*DD + d] = v;
  }
  for (int j = 0; j < 3; j++){
    const float* vr = vew + ((size_t)j*NV + tok) * DD;
    float* dst = veg + ((size_t)j*TT + t) * DD;
    for (int d = threadIdx.x; d < DD; d += blockDim.x) dst[d] = vr[d];
  }
}

// ---------- row rmsnorm -> bf16 ----------
__global__ void k_rmsnorm_bf(const float* __restrict__ in, u16* __restrict__ out){
  int t = blockIdx.x;
  const float* r = in + (size_t)t * DD;
  float ss = 0.f;
  for (int d = threadIdx.x; d < DD; d += blockDim.x){ float v = r[d]; ss += v*v; }
  float tot = block_sum(ss);
  float rn = rsqrtf(tot / DD + EPSF);
  u16* o = out + (size_t)t * DD;
  for (int d = threadIdx.x; d < DD; d += blockDim.x) o[d] = f2bf(r[d] * rn);
}

// ---------- MFMA bf16 GEMM: C[M,N] (+)= A[M,K] * B[N,K]^T ----------
// 128x128 tile, BK=64, 256 threads (4 waves 2x2), 16x16x32 MFMA.
template<int BETA>
__global__ __launch_bounds__(256) void k_mfma_gemm(const u16* __restrict__ A, const u16* __restrict__ B,
                                                   float* __restrict__ C, int N, int K){
  __shared__ u16 As[128*64];
  __shared__ u16 Bs[128*64];
  int tid = threadIdx.x;
  int wid = tid >> 6, lane = tid & 63;
  int wr = wid >> 1, wc = wid & 1;
  int bm = blockIdx.y * 128, bn = blockIdx.x * 128;
  int srow = lane >> 3;           // 0..7 within chunk
  int scol = (lane & 7) * 8;      // bf16 col within 64
  int l15 = lane & 15, l16 = lane >> 4;
  f32x4 acc[4][4] = {};
  for (int k0 = 0; k0 < K; k0 += 64){
#pragma unroll
    for (int c = 0; c < 4; c++){
      int chunk = wid * 4 + c;
      int row = chunk * 8 + srow;
      async16(A + (size_t)(bm + row) * K + k0 + scol, As + chunk * 512);
      async16(B + (size_t)(bn + row) * K + k0 + scol, Bs + chunk * 512);
    }
    __syncthreads();
#pragma unroll
    for (int kk = 0; kk < 2; kk++){
      short8v a[4], b[4];
#pragma unroll
      for (int m = 0; m < 4; m++)
        a[m] = *(const short8v*)(As + (wr*64 + m*16 + l15)*64 + kk*32 + l16*8);
#pragma unroll
      for (int n = 0; n < 4; n++)
        b[n] = *(const short8v*)(Bs + (wc*64 + n*16 + l15)*64 + kk*32 + l16*8);
#pragma unroll
      for (int m = 0; m < 4; m++)
#pragma unroll
        for (int n = 0; n < 4; n++)
          acc[m][n] = __builtin_amdgcn_mfma_f32_16x16x32_bf16(a[m], b[n], acc[m][n], 0, 0, 0);
    }
    __syncthreads();
  }
#pragma unroll
  for (int m = 0; m < 4; m++){
    int row = bm + wr*64 + m*16 + l16*4;
#pragma unroll
    for (int j = 0; j < 4; j++){
      float* cp = C + (size_t)(row + j) * N + bn + wc*64 + l15;
#pragma unroll
      for (int n = 0; n < 4; n++){
        if (BETA) cp[n*16] += acc[m][n][j];
        else      cp[n*16]  = acc[m][n][j];
      }
    }
  }
}

// ---------- lm_head MFMA GEMM fused with logit transform + expsum ----------
__global__ __launch_bounds__(256) void k_loss_mfma(const u16* __restrict__ A, const u16* __restrict__ B,
                                                   const int* __restrict__ tgt, float* __restrict__ rowsum,
                                                   float* __restrict__ tl){
  __shared__ u16 As[128*64];
  __shared__ u16 Bs[128*64];
  int tid = threadIdx.x;
  int wid = tid >> 6, lane = tid & 63;
  int wr = wid >> 1, wc = wid & 1;
  int bm = blockIdx.y * 128, bn = blockIdx.x * 128;
  int srow = lane >> 3, scol = (lane & 7) * 8;
  int l15 = lane & 15, l16 = lane >> 4;
  f32x4 acc[4][4] = {};
  for (int k0 = 0; k0 < DD; k0 += 64){
#pragma unroll
    for (int c = 0; c < 4; c++){
      int chunk = wid * 4 + c;
      int row = chunk * 8 + srow;
      async16(A + (size_t)(bm + row) * DD + k0 + scol, As + chunk * 512);
      async16(B + (size_t)(bn + row) * DD + k0 + scol, Bs + chunk * 512);
    }
    __syncthreads();
#pragma unroll
    for (int kk = 0; kk < 2; kk++){
      short8v a[4], b[4];
#pragma unroll
      for (int m = 0; m < 4; m++)
        a[m] = *(const short8v*)(As + (wr*64 + m*16 + l15)*64 + kk*32 + l16*8);
#pragma unroll
      for (int n = 0; n < 4; n++)
        b[n] = *(const short8v*)(Bs + (wc*64 + n*16 + l15)*64 + kk*32 + l16*8);
#pragma unroll
      for (int m = 0; m < 4; m++)
#pragma unroll
        for (int n = 0; n < 4; n++)
          acc[m][n] = __builtin_amdgcn_mfma_f32_16x16x32_bf16(a[m], b[n], acc[m][n], 0, 0, 0);
    }
    __syncthreads();
  }
  const float INVS = 0.0048112522432469f; // 1/(7.5*sqrt(768))
#pragma unroll
  for (int m = 0; m < 4; m++){
#pragma unroll
    for (int j = 0; j < 4; j++){
      int row = bm + wr*64 + m*16 + l16*4 + j;
      int tg = tgt[row];
      float rs = 0.f;
#pragma unroll
      for (int n = 0; n < 4; n++){
        int col = bn + wc*64 + n*16 + l15;
        float lg = 30.f / (1.f + expf(-acc[m][n][j] * INVS));
        rs += expf(lg);
        if (col == tg) tl[row] = lg;
      }
      rs += __shfl_xor(rs, 1); rs += __shfl_xor(rs, 2);
      rs += __shfl_xor(rs, 4); rs += __shfl_xor(rs, 8);
      if (l15 == 0) atomicAdd(&rowsum[row], rs);
    }
  }
}

// ---------- per-head q/k rmsnorm + rotary (one wave per (t,h)) ----------
__global__ void k_qknorm_rope(float* __restrict__ qkv, const float* __restrict__ cosb,
                              const float* __restrict__ sinb){
  int wv = threadIdx.x >> 6, lane = threadIdx.x & 63;
  int idx = blockIdx.x * 4 + wv;
  int t = idx / HH, h = idx - t * HH;
  float c = cosb[t*64 + lane], s = sinb[t*64 + lane];
#pragma unroll
  for (int w = 0; w < 2; w++){
    float* p = qkv + (size_t)t*2304 + w*768 + h*HDIM;
    float v1 = p[lane], v2 = p[lane + 64];
    float ss = wave_sum(v1*v1 + v2*v2);
    float rn = rsqrtf(ss / 128.f + EPSF);
    v1 *= rn; v2 *= rn;
    p[lane]      = v1 * c + v2 * s;
    p[lane + 64] = -v1 * s + v2 * c;
  }
}

// ---------- v = lam0*v + lam1*ve ----------
__global__ void k_vmix(float* __restrict__ qkv, const float* __restrict__ ve,
                       const float* __restrict__ lam, int layer){
  int i = blockIdx.x * 256 + threadIdx.x;
  float l0 = lam[layer*2], l1 = lam[layer*2 + 1];
  int t = i / DD, d = i - t * DD;
  float* vp = qkv + (size_t)t*2304 + 1536 + d;
  float v = *vp * l0;
  if (ve) v += l1 * ve[i];
  *vp = v;
}

// ---------- fused attention with block-skip; bf16 output ----------
#define QR 8
__global__ __launch_bounds__(256) void k_attn(const float* __restrict__ qkv, u16* __restrict__ y,
                                              const int* __restrict__ docs,
                                              const int* __restrict__ kfm, const int* __restrict__ kpm){
  __shared__ float sc[QR][TT];     // 64 KB (compact-indexed)
  __shared__ float qs[QR][HDIM];   // 4 KB
  __shared__ float rinv[QR];
  __shared__ int kb[NBL], kfl[NBL], nkb_sh;
  int h = blockIdx.x;
  int r0 = blockIdx.y * QR;
  int tid = threadIdx.x;
  int bt = r0 >> 7;
  if (tid == 0){
    int n = 0;
    for (int sb = 0; sb <= bt; sb++){
      int kf = kfm[bt*NBL + sb], kp = kpm[bt*NBL + sb];
      if (kf || kp){ kb[n] = sb; kfl[n] = kf; n++; }
    }
    nkb_sh = n;
  }
  for (int i = tid; i < QR*HDIM; i += 256){
    int r = i >> 7, d = i & 127;
    qs[r][d] = qkv[(size_t)(r0 + r)*2304 + h*HDIM + d];
  }
  __syncthreads();
  int L = nkb_sh * 128;
  int dq[QR];
#pragma unroll
  for (int r = 0; r < QR; r++) dq[r] = docs[r0 + r];
  for (int ci = tid; ci < L; ci += 256){
    int blk = ci >> 7;
    int s = kb[blk]*128 + (ci & 127);
    const float* kr = qkv + (size_t)s*2304 + 768 + h*HDIM;
    float acc[QR] = {};
#pragma unroll 8
    for (int d = 0; d < HDIM; d += 4){
      float4 kv = *(const float4*)(kr + d);
#pragma unroll
      for (int r = 0; r < QR; r++)
        acc[r] += kv.x*qs[r][d] + kv.y*qs[r][d+1] + kv.z*qs[r][d+2] + kv.w*qs[r][d+3];
    }
    int kf = kfl[blk];
    int ds = docs[s];
#pragma unroll
    for (int r = 0; r < QR; r++){
      int t = r0 + r;
      bool m = kf || ((s <= t) && (ds == dq[r]));
      sc[r][ci] = m ? acc[r] * 0.12f : -1e30f;
    }
  }
  __syncthreads();
  int wv = tid >> 6, lane = tid & 63;
  for (int r = wv; r < QR; r += 4){
    float mx = -1e30f;
    for (int ci = lane; ci < L; ci += 64) mx = fmaxf(mx, sc[r][ci]);
    mx = wave_max(mx);
    float sum = 0.f;
    for (int ci = lane; ci < L; ci += 64){ float e = __expf(sc[r][ci] - mx); sc[r][ci] = e; sum += e; }
    sum = wave_sum(sum);
    if (lane == 0) rinv[r] = 1.f / sum;
  }
  __syncthreads();
  int r = tid >> 5, c4 = tid & 31;
  const float* vb = qkv + 1536 + h*HDIM + c4*4;
  float ax = 0, ay = 0, az = 0, aw = 0;
  for (int ci = 0; ci < L; ci++){
    int s = kb[ci >> 7]*128 + (ci & 127);
    float p = sc[r][ci];
    float4 vv = *(const float4*)(vb + (size_t)s*2304);
    ax += p*vv.x; ay += p*vv.y; az += p*vv.z; aw += p*vv.w;
  }
  float inv = rinv[r];
  u16 o[4] = { f2bf(ax*inv), f2bf(ay*inv), f2bf(az*inv), f2bf(aw*inv) };
  *(ushort4*)(y + (size_t)(r0 + r)*DD + h*HDIM + c4*4) = *(const ushort4*)o;
}

// ---------- elementwise ----------
__global__ void k_relusq_bf(const float* __restrict__ h, u16* __restrict__ o){
  int i = blockIdx.x * 256 + threadIdx.x;
  float v = h[i]; v = fmaxf(v, 0.f); o[i] = f2bf(v * v);
}
__global__ void k_blockmix(float* __restrict__ x, const float* __restrict__ x0,
                           const float* __restrict__ bl, int layer){
  int i = blockIdx.x * 256 + threadIdx.x;
  x[i] = bl[layer*2] * x[i] + bl[layer*2 + 1] * x0[i];
}
__global__ void k_skipadd(float* __restrict__ x, const float* __restrict__ sk,
                          const float* __restrict__ sw, int j){
  int i = blockIdx.x * 256 + threadIdx.x;
  x[i] += sw[j] * sk[i];
}

__global__ void k_loss_final(const float* __restrict__ rowsum, const float* __restrict__ tl,
                             float* __restrict__ out){
  float a = 0.f;
  for (int t = threadIdx.x; t < TT; t += 256) a += logf(rowsum[t]) - tl[t];
  a = block_sum(a);
  if (threadIdx.x == 0) out[0] = a / TT;
}

extern "C" void kernel_launch(void* const* d_in, const int* in_sizes, int n_in,
                              void* d_out, int out_size, void* d_ws, size_t ws_size,
                              hipStream_t stream){
  const int*   seq   = (const int*)d_in[0];
  const int*   tgt   = (const int*)d_in[1];
  const int*   swnb  = (const int*)d_in[2];
  const float* embw  = (const float*)d_in[3];
  const float* vew   = (const float*)d_in[4];
  const float* qkvw  = (const float*)d_in[5];
  const float* alam  = (const float*)d_in[6];
  const float* aproj = (const float*)d_in[7];
  const float* fcw   = (const float*)d_in[8];
  const float* mproj = (const float*)d_in[9];
  const float* blam  = (const float*)d_in[10];
  const float* skw   = (const float*)d_in[11];
  const float* lmw   = (const float*)d_in[12];

  char* base = (char*)d_ws;
  size_t off = 0;
  auto alloc = [&](size_t bytes){ char* p = base + off; off += (bytes + 255) & ~(size_t)255; return p; };
  float* x     = (float*)alloc((size_t)TT*DD*4);
  float* x0    = (float*)alloc((size_t)TT*DD*4);
  float* qkv   = (float*)alloc((size_t)TT*2304*4);
  float* hbuf  = (float*)alloc((size_t)TT*DFF*4);
  float* veg   = (float*)alloc((size_t)3*TT*DD*4);
  float* skips = (float*)alloc((size_t)6*TT*DD*4);
  float* cosb  = (float*)alloc((size_t)TT*64*4);
  float* sinb  = (float*)alloc((size_t)TT*64*4);
  float* rowsum= (float*)alloc(TT*4);
  float* tl    = (float*)alloc(TT*4);
  int* docs    = (int*)alloc(TT*4);
  int* bmask   = (int*)alloc(4*NBL*NBL*4);
  u16* xn_bf   = (u16*)alloc((size_t)TT*DD*2);
  u16* y_bf    = (u16*)alloc((size_t)TT*DD*2);
  u16* hb_bf   = (u16*)alloc((size_t)TT*DFF*2);
  u16* qkvw_bf = (u16*)alloc((size_t)NL*2304*DD*2);
  u16* aprojw_bf = (u16*)alloc((size_t)NL*DD*DD*2);
  u16* fcw_bf  = (u16*)alloc((size_t)NL*DFF*DD*2);
  u16* mprojw_bf = (u16*)alloc((size_t)NL*DD*DFF*2);
  u16* lmw_bf  = (u16*)alloc((size_t)VP*DD*2);

  // weight conversions (deterministic, every call)
  k_f2bf<<<2048, 256, 0, stream>>>(qkvw,  qkvw_bf,  (long)NL*2304*DD/8);
  k_f2bf<<<1024, 256, 0, stream>>>(aproj, aprojw_bf,(long)NL*DD*DD/8);
  k_f2bf<<<2048, 256, 0, stream>>>(fcw,   fcw_bf,   (long)NL*DFF*DD/8);
  k_f2bf<<<2048, 256, 0, stream>>>(mproj, mprojw_bf,(long)NL*DD*DFF/8);
  k_f2bf<<<2048, 256, 0, stream>>>(lmw,   lmw_bf,   (long)VP*DD/8);

  k_docs_masks<<<1, 64, 0, stream>>>(seq, swnb, docs, bmask);
  k_rotary<<<TT, 64, 0, stream>>>(cosb, sinb);
  k_embed<<<TT, 256, 0, stream>>>(seq, embw, vew, x, x0, veg);

  static const int msel[12] = {0,1,1,1,0,1, 1,0,1,1,1,0};
  const int NE = TT*DD/256;
  for (int i = 0; i < NL; i++){
    if (i >= 6){
      int j = i - 6;
      k_skipadd<<<NE, 256, 0, stream>>>(x, skips + (size_t)(5 - j)*TT*DD, skw, j);
    }
    k_blockmix<<<NE, 256, 0, stream>>>(x, x0, blam, i);
    if (i != 7){
      k_rmsnorm_bf<<<TT, 256, 0, stream>>>(x, xn_bf);
      dim3 g1(2304/128, TT/128);
      k_mfma_gemm<0><<<g1, 256, 0, stream>>>(xn_bf, qkvw_bf + (size_t)i*2304*DD, qkv, 2304, DD);
      k_qknorm_rope<<<TT*HH/4, 256, 0, stream>>>(qkv, cosb, sinb);
      const float* vp = nullptr;
      if (i < 3) vp = veg + (size_t)i*TT*DD;
      else if (i >= 9) vp = veg + (size_t)(i - 9)*TT*DD;
      k_vmix<<<NE, 256, 0, stream>>>(qkv, vp, alam, i);
      const int* kfm = bmask + (msel[i]*2 + 0)*NBL*NBL;
      const int* kpm = bmask + (msel[i]*2 + 1)*NBL*NBL;
      dim3 ga(HH, TT/QR);
      k_attn<<<ga, 256, 0, stream>>>(qkv, y_bf, docs, kfm, kpm);
      dim3 g2(DD/128, TT/128);
      k_mfma_gemm<1><<<g2, 256, 0, stream>>>(y_bf, aprojw_bf + (size_t)i*DD*DD, x, DD, DD);
    }
    k_rmsnorm_bf<<<TT, 256, 0, stream>>>(x, xn_bf);
    dim3 g3(DFF/128, TT/128);
    k_mfma_gemm<0><<<g3, 256, 0, stream>>>(xn_bf, fcw_bf + (size_t)i*DFF*DD, hbuf, DFF, DD);
    k_relusq_bf<<<TT*DFF/256, 256, 0, stream>>>(hbuf, hb_bf);
    dim3 g4(DD/128, TT/128);
    k_mfma_gemm<1><<<g4, 256, 0, stream>>>(hb_bf, mprojw_bf + (size_t)i*DD*DFF, x, DD, DFF);
    if (i < 6){
      hipMemcpyAsync(skips + (size_t)i*TT*DD, x, (size_t)TT*DD*sizeof(float),
                     hipMemcpyDeviceToDevice, stream);
    }
  }
  k_rmsnorm_bf<<<TT, 256, 0, stream>>>(x, xn_bf);
  hipMemsetAsync(rowsum, 0, TT*sizeof(float), stream);
  dim3 g5(VP/128, TT/128);
  k_loss_mfma<<<g5, 256, 0, stream>>>(xn_bf, lmw_bf, tgt, rowsum, tl);
  k_loss_final<<<1, 256, 0, stream>>>(rowsum, tl, (float*)d_out);
}